// Round 9
// baseline (2866.381 us; speedup 1.0000x reference)
//
#include <hip/hip_runtime.h>

// Problem constants
#define TT 512
#define BB 256
#define II 128
#define HH 256
#define CC 10

typedef __attribute__((ext_vector_type(8))) _Float16 f16x8;
typedef __attribute__((ext_vector_type(4))) _Float16 f16x4;
typedef __attribute__((ext_vector_type(4))) float    f32x4;

__device__ __forceinline__ float fsig(float x){ return 1.0f/(1.0f+__expf(-x)); }
__device__ __forceinline__ float ftanh(float x){ return 2.0f/(1.0f+__expf(-2.0f*x)) - 1.0f; }

// ---- R12 design ------------------------------------------------------------
// Established: R7 (XCD-scope RMW poll + plain-store data path) = 1380us
// dispatch; its ~2.7us/step is EXPOSED serial latency (poll-detect + h-load
// + MFMA + EW + drain), not contention (R11 falsified queueing). Load-polls
// never observe remote updates (R9/R10); only RMW observes promptly.
// R12: each wave runs TWO chains (groups set, set+8; same gj -> shared weight
// regs). Release checks use ASYNC RMW SAMPLES: a returning atomic_add(0)
// issued one slot early, waited via a tied vmcnt(0) at the check point.
// If sample >= target: issue the other chain's loads (safe: the sample
// completed at L2 BEFORE the loads issue, so all peer stores -- which
// precede their arrives -- precede the loads). Loads then complete under
// this chain's EW+drain. Blocking poll (R7 primitive) remains only as the
// sample-miss fallback. Only vmcnt(0) waits anywhere (R5's counted-vmcnt
// crash class eliminated). Deadlock-free: arrives unconditional per step.

// Blocking RMW poll (R7-proven observer). Lane0 spins, broadcast.
template<bool FAST>
__device__ __forceinline__ unsigned poll_rmw(unsigned* p, unsigned tgt){
  unsigned v = 0;
  if((threadIdx.x & 63) == 0){
    if constexpr(FAST){
      unsigned z = 0u;
      asm volatile("global_atomic_add %0, %1, %2, off sc0\n\ts_waitcnt vmcnt(0)"
                   : "=v"(v) : "v"(p), "v"(z) : "memory");
      while(v < tgt){
        __builtin_amdgcn_s_sleep(2);
        asm volatile("global_atomic_add %0, %1, %2, off sc0\n\ts_waitcnt vmcnt(0)"
                     : "=v"(v) : "v"(p), "v"(z) : "memory");
      }
    } else {
      v = __hip_atomic_fetch_add(p, 0u, __ATOMIC_RELAXED, __HIP_MEMORY_SCOPE_AGENT);
      while(v < tgt){ __builtin_amdgcn_s_sleep(2);
        v = __hip_atomic_fetch_add(p, 0u, __ATOMIC_RELAXED, __HIP_MEMORY_SCOPE_AGENT); }
    }
  }
  unsigned u = __builtin_amdgcn_readfirstlane(v);
  asm volatile("" ::: "memory");
  return u;
}
// Async sample: returning RMW issued WITHOUT wait; result consumed only
// after a later tied vmcnt(0). Slow path: synchronous agent RMW (correctness).
template<bool FAST>
__device__ __forceinline__ unsigned sample_rmw(unsigned* p){
  if constexpr(FAST){
    unsigned v, z = 0u;
    asm volatile("global_atomic_add %0, %1, %2, off sc0"
                 : "=v"(v) : "v"(p), "v"(z) : "memory");
    return v;
  } else {
    return __hip_atomic_fetch_add(p, 0u, __ATOMIC_RELAXED, __HIP_MEMORY_SCOPE_AGENT);
  }
}
// Fire-and-forget arrive (+1).
template<bool FAST>
__device__ __forceinline__ void arrive1(unsigned* p){
  if((threadIdx.x & 63) == 0){
    if constexpr(FAST){
      unsigned one = 1u;
      asm volatile("global_atomic_add %0, %1, off" :: "v"(p), "v"(one) : "memory");
    } else {
      (void)__hip_atomic_fetch_add(p, 1u, __ATOMIC_RELAXED, __HIP_MEMORY_SCOPE_AGENT);
    }
  }
}
// Publish h. FAST: plain store -> local L2. slow: write-through IF$.
template<bool FAST>
__device__ __forceinline__ void store_h16(_Float16* p, _Float16 vv){
  unsigned b32 = (unsigned)__builtin_bit_cast(unsigned short, vv);
  if constexpr(FAST)
    asm volatile("global_store_short %0, %1, off" :: "v"(p), "v"(b32) : "memory");
  else
    asm volatile("global_store_short %0, %1, off sc0 sc1" :: "v"(p), "v"(b32) : "memory");
}
// Ring load (addresses reused every 4 steps -> bypass CU L1).
template<bool FAST>
__device__ __forceinline__ void ld16_ring(f16x8& r, const _Float16* p){
  if constexpr(FAST)
    asm volatile("global_load_dwordx4 %0, %1, off sc0" : "=v"(r) : "v"(p) : "memory");
  else
    asm volatile("global_load_dwordx4 %0, %1, off sc0 sc1" : "=v"(r) : "v"(p) : "memory");
}
// Plain cached load via asm (issue-point control; fresh addresses only).
__device__ __forceinline__ void ld16_pl(f16x8& r, const _Float16* p){
  asm volatile("global_load_dwordx4 %0, %1, off" : "=v"(r) : "v"(p) : "memory");
}
#define PIN(x) asm volatile("" : "+v"(x))
#define TIE4(A) "+v"(A[0]),"+v"(A[1]),"+v"(A[2]),"+v"(A[3])
#define TIE8(A) TIE4(A),"+v"(A[4]),"+v"(A[5]),"+v"(A[6]),"+v"(A[7])

// Elementwise cell update + h publish (4 cells/lane).
template<bool FAST>
__device__ __forceinline__ void ew_store(int t, f32x4 acc[4], float* cs, float* hs,
    const int* len, _Float16* hbase, int sb0, int u){
#pragma unroll
  for(int r=0; r<4; ++r){
    float iv = fsig (acc[0][r]);
    float fv = fsig (acc[1][r]);
    float gv = ftanh(acc[2][r]);
    float ov = fsig (acc[3][r]);
    float cn_ = fv*cs[r] + iv*gv;
    float hn  = ov*ftanh(cn_);
    if(t < len[r]){ cs[r] = cn_; hs[r] = hn; }
    store_h16<FAST>(hbase + (size_t)(sb0+r)*HH + u, (_Float16)hs[r]);
  }
}

// One WAVE owns TWO groups (chains) x 16 units x 4 gates. Same gj -> weights
// shared in VGPRs. Slot order per t: chain0, chain1.
template<int KXT, bool IS_L1, bool FAST>
__device__ __forceinline__ void run_wave2(
    const _Float16* __restrict__ xin,   // L0: xc [B][T][I] ; L1: h0 [T][B][H]
    const _Float16* __restrict__ Wh,    // fp16 [4H][H]
    const _Float16* __restrict__ Wx,    // fp16 [4H][KXT*32]
    const float* __restrict__ b_ih, const float* __restrict__ b_hh,
    const int* __restrict__ lengths,
    _Float16* __restrict__ hbuf,        // L0: h0 full [T][B][H]; L1: ring [4][B][H]
    float* __restrict__ hT,
    unsigned* cownA, unsigned* cownB,   // own-group counters (chain 0/1)
    unsigned* cprodA, unsigned* cprodB, // producer counters (L1 only)
    int set, int gj)
{
  constexpr int KXV = KXT*32;
  const int lane = threadIdx.x & 63;
  const int quad = lane >> 4;
  const int l15  = lane & 15;
  const int koff = quad << 3;
  const int u    = (gj << 4) + l15;

  // Stationary weight fragments (shared by both chains), pinned.
  f16x8 wh[4][8], wx[4][KXT];
  float bias[4];
#pragma unroll
  for(int g=0; g<4; ++g){
    const int row = g*HH + u;
#pragma unroll
    for(int kt=0; kt<8; ++kt){
      wh[g][kt] = *(const f16x8*)(Wh + (size_t)row*HH + kt*32 + koff);
      PIN(wh[g][kt]);
    }
#pragma unroll
    for(int kt=0; kt<KXT; ++kt){
      wx[g][kt] = *(const f16x8*)(Wx + (size_t)row*KXV + kt*32 + koff);
      PIN(wx[g][kt]);
    }
    bias[g] = b_ih[row] + b_hh[row];
  }

  const int gb[2] = {set, set + 8};
  unsigned* cown [2] = {cownA, cownB};
  unsigned* cprod[2] = {cprodA, cprodB};
  int len[2][4]; float cs[2][4], hs[2][4];
#pragma unroll
  for(int c=0; c<2; ++c){
    const int sb0 = gb[c]*16 + quad*4;
#pragma unroll
    for(int r=0; r<4; ++r){
      len[c][r] = lengths[sb0+r];
      cs[c][r] = 0.f; hs[c][r] = 0.f;
    }
  }

  f16x8 ah[8], ax[KXT];                 // shared prefetch buffers (alternating)
  unsigned sampO[2] = {0,0}, sampP[2] = {0,0};
  bool pfok[2] = {false,false};

  // helpers (compile-time c via unrolled callers)
  auto LOADAH = [&](int gbase, int t){
    if constexpr(IS_L1){
      const _Float16* hp = hbuf + (((size_t)((t-1)&3))*BB + gbase + l15)*HH + koff;
#pragma unroll
      for(int kt=0; kt<8; ++kt) ld16_ring<FAST>(ah[kt], hp + kt*32);
    } else {
      const _Float16* hp = hbuf + ((size_t)(t-1)*BB + gbase + l15)*HH + koff;
#pragma unroll
      for(int kt=0; kt<8; ++kt) ld16_pl(ah[kt], hp + kt*32);
    }
  };
  auto LOADAX = [&](int gbase, int t){
    if constexpr(IS_L1){
      const _Float16* xp = xin + ((size_t)t*BB + gbase + l15)*HH + koff;
#pragma unroll
      for(int kt=0; kt<KXT; ++kt) ld16_pl(ax[kt], xp + kt*32);
    } else {
      const _Float16* xp = xin + ((size_t)(gbase + l15)*TT + t)*KXV + koff;
#pragma unroll
      for(int kt=0; kt<KXT; ++kt) ld16_pl(ax[kt], xp + kt*32);
    }
  };

  // ---------------- prologue: t=0 both chains (x-part only) -----------------
#pragma unroll
  for(int c=0; c<2; ++c){
    if constexpr(IS_L1) poll_rmw<FAST>(cprod[c], 16u);
    LOADAX(gb[c]*16, 0);
    if constexpr(KXT==8) asm volatile("s_waitcnt vmcnt(0)" : TIE8(ax) :: "memory");
    else                 asm volatile("s_waitcnt vmcnt(0)" : TIE4(ax) :: "memory");
    __builtin_amdgcn_sched_barrier(0);
    f32x4 acc[4];
#pragma unroll
    for(int g=0; g<4; ++g) acc[g] = (f32x4){bias[g],bias[g],bias[g],bias[g]};
#pragma unroll
    for(int kt=0; kt<KXT; ++kt)
#pragma unroll
      for(int g=0; g<4; ++g)
        acc[g] = __builtin_amdgcn_mfma_f32_16x16x32_f16(ax[kt], wx[g][kt], acc[g], 0,0,0);
    ew_store<FAST>(0, acc, cs[c], hs[c], len[c], hbuf, gb[c]*16 + quad*4, u);
    asm volatile("s_waitcnt vmcnt(0)" ::: "memory");
    arrive1<FAST>(cown[c]);
  }
  // ---------------- prime: blocking acquire for slot (0,1); sample chain 1 --
  poll_rmw<FAST>(cown[0], 16u);
  if constexpr(IS_L1) poll_rmw<FAST>(cprod[0], 32u);
  LOADAH(gb[0]*16, 1); LOADAX(gb[0]*16, 1);
  pfok[0] = true;
  if(lane == 0){
    sampO[1] = sample_rmw<FAST>(cown[1]);
    if constexpr(IS_L1) sampP[1] = sample_rmw<FAST>(cprod[1]);
  }

  // ---------------- main loop: t = 1..TT-1, slots c = 0,1 --------------------
#pragma unroll 1
  for(int t=1; t<TT; ++t){
#pragma unroll
    for(int c=0; c<2; ++c){
      const int cn = 1-c;
      const int tn = (c==0) ? t : t+1;

      // A: ensure this chain's inputs are ready
      if(!pfok[c]){
        poll_rmw<FAST>(cown[c], 16u*(unsigned)t);
        if constexpr(IS_L1) poll_rmw<FAST>(cprod[c], 16u*(unsigned)(t+1));
        LOADAH(gb[c]*16, t); LOADAX(gb[c]*16, t);
      }
      if constexpr(KXT==8) asm volatile("s_waitcnt vmcnt(0)" : TIE8(ah), TIE8(ax) :: "memory");
      else                 asm volatile("s_waitcnt vmcnt(0)" : TIE8(ah), TIE4(ax) :: "memory");
      __builtin_amdgcn_sched_barrier(0);

      // B: x-MFMAs
      f32x4 acc[4];
#pragma unroll
      for(int g=0; g<4; ++g) acc[g] = (f32x4){bias[g],bias[g],bias[g],bias[g]};
#pragma unroll
      for(int kt=0; kt<KXT; ++kt)
#pragma unroll
        for(int g=0; g<4; ++g)
          acc[g] = __builtin_amdgcn_mfma_f32_16x16x32_f16(ax[kt], wx[g][kt], acc[g], 0,0,0);
      // D: h-MFMAs (frees ah/ax for the prefetch below)
#pragma unroll
      for(int kt=0; kt<8; ++kt)
#pragma unroll
        for(int g=0; g<4; ++g)
          acc[g] = __builtin_amdgcn_mfma_f32_16x16x32_f16(ah[kt], wh[g][kt], acc[g], 0,0,0);
      __builtin_amdgcn_sched_barrier(0);   // keep MFMAs above the ah/ax overwrite

      // C: other chain's release check via 1-slot-old sample; prefetch if ok
      if(tn < TT){
        asm volatile("s_waitcnt vmcnt(0)"
                     : "+v"(sampO[cn]), "+v"(sampP[cn]) :: "memory");
        __builtin_amdgcn_sched_barrier(0);
        unsigned so = __builtin_amdgcn_readfirstlane(sampO[cn]);
        bool ok = (so >= 16u*(unsigned)tn);
        if constexpr(IS_L1){
          unsigned sp = __builtin_amdgcn_readfirstlane(sampP[cn]);
          ok = ok && (sp >= 16u*(unsigned)(tn+1));
        }
        pfok[cn] = ok;
        if(ok){ LOADAH(gb[cn]*16, tn); LOADAX(gb[cn]*16, tn); }  // complete under E/F
      }

      // E: elementwise + publish h[t]
      {
        _Float16* hbase = IS_L1 ? hbuf + (size_t)(t&3)*BB*HH
                                : hbuf + (size_t)t*BB*HH;
        const int sb0 = gb[c]*16 + quad*4;
        ew_store<FAST>(t, acc, cs[c], hs[c], len[c], hbase, sb0, u);
        if constexpr(IS_L1){
          if(t == TT-1){
#pragma unroll
            for(int r=0; r<4; ++r) hT[(size_t)(sb0+r)*HH + u] = hs[c][r];
          }
        }
      }

      // F: drain stores (+prefetch), arrive, issue own next-step samples
      asm volatile("s_waitcnt vmcnt(0)" ::: "memory");
      arrive1<FAST>(cown[c]);
      if(t+1 < TT){
        if(lane == 0){
          sampO[c] = sample_rmw<FAST>(cown[c]);
          if constexpr(IS_L1) sampP[c] = sample_rmw<FAST>(cprod[c]);
        }
      }
    }
  }
}

// 256 single-wave WGs (1/CU). blk<128: L0 (set=blk&7, gj=blk>>3); else L1.
// All 32 communicating waves of a super-group (L0 set, set+8 + L1 partners)
// have blk%8==set -> one XCD under round-robin. Handshake verifies; slow
// agent-scope path otherwise (G16: correctness never depends on placement).
__global__ __launch_bounds__(64, 1)
void lstm_fused(const _Float16* __restrict__ xc,
                const _Float16* __restrict__ Wh0, const _Float16* __restrict__ Wx0,
                const _Float16* __restrict__ Wh1, const _Float16* __restrict__ Wx1,
                const float* __restrict__ b_ih0, const float* __restrict__ b_hh0,
                const float* __restrict__ b_ih1, const float* __restrict__ b_hh1,
                const int* __restrict__ lens,
                _Float16* __restrict__ h0seq, _Float16* __restrict__ h1ring,
                float* __restrict__ hT, unsigned* __restrict__ ctr)
{
  const int blk  = blockIdx.x;
  const bool L1k = blk >= 128;
  const int  i   = L1k ? blk - 128 : blk;
  const int  set = i & 7;
  const int  gj  = i >> 3;
  const int lane = threadIdx.x & 63;
  unsigned* c0a = ctr + set*32;            // L0 group set
  unsigned* c0b = ctr + (set+8)*32;        // L0 group set+8
  unsigned* c1a = ctr + (16+set)*32;       // L1 group set
  unsigned* c1b = ctr + (16+set+8)*32;     // L1 group set+8
  unsigned* xcds  = ctr + 1024;            // [256] XCC ids (ws+4K)
  unsigned* cinit = ctr + 1536;            // startup barrier (ws+6K)

  // ---- one-time colocation handshake (agent scope, proven primitives) ----
  unsigned myx;
  asm volatile("s_getreg_b32 %0, hwreg(HW_REG_XCC_ID)" : "=s"(myx));
  if(lane == 0){
    asm volatile("global_store_dword %0, %1, off sc0 sc1" :: "v"(xcds + blk), "v"(myx) : "memory");
    asm volatile("s_waitcnt vmcnt(0)" ::: "memory");
    (void)__hip_atomic_fetch_add(cinit, 1u, __ATOMIC_RELAXED, __HIP_MEMORY_SCOPE_AGENT);
  }
  unsigned iv = 0;
  if(lane == 0){
    iv = __hip_atomic_fetch_add(cinit, 0u, __ATOMIC_RELAXED, __HIP_MEMORY_SCOPE_AGENT);
    while(iv < 256u){ __builtin_amdgcn_s_sleep(8);
      iv = __hip_atomic_fetch_add(cinit, 0u, __ATOMIC_RELAXED, __HIP_MEMORY_SCOPE_AGENT); }
  }
  (void)__builtin_amdgcn_readfirstlane(iv);
  asm volatile("" ::: "memory");
  // lanes 0-15: L0 blocks set+8j ; lanes 16-31: L1 blocks 128+set+8j
  unsigned pv = myx;
  if(lane < 32){
    const unsigned* pp = xcds + ((lane < 16) ? (set + 8*lane)
                                             : (128 + set + 8*(lane-16)));
    asm volatile("global_load_dword %0, %1, off sc0 sc1\n\ts_waitcnt vmcnt(0)"
                 : "=v"(pv) : "v"(pp) : "memory");
  }
  const bool fast = (__ballot(pv == myx) == ~0ull);

  if(!L1k){
    if(fast) run_wave2<4,false,true >(xc, Wh0, Wx0, b_ih0, b_hh0, lens, h0seq,
                                      nullptr, c0a, c0b, nullptr, nullptr, set, gj);
    else     run_wave2<4,false,false>(xc, Wh0, Wx0, b_ih0, b_hh0, lens, h0seq,
                                      nullptr, c0a, c0b, nullptr, nullptr, set, gj);
  } else {
    if(fast) run_wave2<8,true ,true >(h0seq, Wh1, Wx1, b_ih1, b_hh1, lens, h1ring,
                                      hT, c1a, c1b, c0a, c0b, set, gj);
    else     run_wave2<8,true ,false>(h0seq, Wh1, Wx1, b_ih1, b_hh1, lens, h1ring,
                                      hT, c1a, c1b, c0a, c0b, set, gj);
  }
}

// fp32 -> fp16 elementwise convert (vectorized x4)
__global__ __launch_bounds__(256)
void cvt4(const float* __restrict__ in, _Float16* __restrict__ out, int n4)
{
  int i = blockIdx.x*256 + threadIdx.x;
  if(i < n4){
    float4 v = ((const float4*)in)[i];
    f16x4 o;
    o[0]=(_Float16)v.x; o[1]=(_Float16)v.y; o[2]=(_Float16)v.z; o[3]=(_Float16)v.w;
    ((f16x4*)out)[i] = o;
  }
}

// logits = hT @ W_fc^T + b_fc ; softmax over 10 classes. One wave per sample.
__global__ __launch_bounds__(64)
void fc_softmax(const float* __restrict__ hT,
                const float* __restrict__ W_fc,
                const float* __restrict__ b_fc,
                float* __restrict__ out)
{
  const int b = blockIdx.x;
  const int lane = threadIdx.x;
  float p[CC];
#pragma unroll
  for (int c = 0; c < CC; ++c) p[c] = 0.f;
  const float* hb = hT + b * HH;
  for (int k = lane; k < HH; k += 64){
    float hv = hb[k];
#pragma unroll
    for (int c = 0; c < CC; ++c) p[c] += hv * W_fc[c * HH + k];
  }
#pragma unroll
  for (int c = 0; c < CC; ++c){
#pragma unroll
    for (int off = 32; off > 0; off >>= 1) p[c] += __shfl_down(p[c], off);
  }
  if (lane == 0){
    float m = -1e30f;
#pragma unroll
    for (int c = 0; c < CC; ++c){ p[c] += b_fc[c]; m = fmaxf(m, p[c]); }
    float ssum = 0.f;
#pragma unroll
    for (int c = 0; c < CC; ++c){ p[c] = __expf(p[c] - m); ssum += p[c]; }
    float inv = 1.0f / ssum;
#pragma unroll
    for (int c = 0; c < CC; ++c) out[b * CC + c] = p[c] * inv;
  }
}

extern "C" void kernel_launch(void* const* d_in, const int* in_sizes, int n_in,
                              void* d_out, int out_size, void* d_ws, size_t ws_size,
                              hipStream_t stream) {
  const float* x      = (const float*)d_in[0];   // [B][T][I]
  const int*   lens   = (const int*)  d_in[1];   // [B]
  const float* W_fc   = (const float*)d_in[2];   // [C][H]
  const float* b_fc   = (const float*)d_in[3];   // [C]
  const float* W_ih0  = (const float*)d_in[4];   // [4H][I]
  const float* W_hh0  = (const float*)d_in[5];   // [4H][H]
  const float* b_ih0  = (const float*)d_in[6];
  const float* b_hh0  = (const float*)d_in[7];
  const float* W_ih1  = (const float*)d_in[8];   // [4H][H]
  const float* W_hh1  = (const float*)d_in[9];
  const float* b_ih1  = (const float*)d_in[10];
  const float* b_hh1  = (const float*)d_in[11];
  float* out = (float*)d_out;

  char* ws = (char*)d_ws;
  // ws layout (bytes):
  //   [0, 4K)          counters (2 layers x 16 groups x 128B)
  //   [4K, 6K)         xcds[256] (handshake)
  //   [6K, 8K)         cinit barrier counter
  //   [8K, +256K)      hT fp32
  //   [270336 ..)      fp16 weights: Wh0(512K) Wx0(256K) Wh1(512K) Wx1(512K)
  //   [2105344 ..)     xc fp16 [B][T][I]  (32 MB)
  //   [35659776 ..)    h0seq fp16 [T][B][H] (64 MB)
  //   [102768640 ..)   h1 ring fp16 [4][B][H] (512 KB)   total ~103 MB
  unsigned* ctr  = (unsigned*)ws;
  float*    hT   = (float*)(ws + 8192);
  _Float16* Wh0c = (_Float16*)(ws + 270336);
  _Float16* Wx0c = (_Float16*)(ws + 794624);
  _Float16* Wh1c = (_Float16*)(ws + 1056768);
  _Float16* Wx1c = (_Float16*)(ws + 1581056);
  _Float16* xc   = (_Float16*)(ws + 2105344);
  _Float16* h0   = (_Float16*)(ws + 35659776);
  _Float16* h1r  = (_Float16*)(ws + 102768640);

  hipMemsetAsync(ws, 0, 8192, stream);   // zero counters + handshake each launch

  // prep: fp32 -> fp16 (weights + x), removes all in-loop conversion work
  cvt4<<<dim3((BB*TT*II/4 + 255)/256), dim3(256), 0, stream>>>(x,     xc,   BB*TT*II/4);
  cvt4<<<dim3((4*HH*HH/4  + 255)/256), dim3(256), 0, stream>>>(W_hh0, Wh0c, 4*HH*HH/4);
  cvt4<<<dim3((4*HH*II/4  + 255)/256), dim3(256), 0, stream>>>(W_ih0, Wx0c, 4*HH*II/4);
  cvt4<<<dim3((4*HH*HH/4  + 255)/256), dim3(256), 0, stream>>>(W_hh1, Wh1c, 4*HH*HH/4);
  cvt4<<<dim3((4*HH*HH/4  + 255)/256), dim3(256), 0, stream>>>(W_ih1, Wx1c, 4*HH*HH/4);

  lstm_fused<<<dim3(256), dim3(64), 0, stream>>>(
      xc, Wh0c, Wx0c, Wh1c, Wx1c, b_ih0, b_hh0, b_ih1, b_hh1, lens,
      h0, h1r, hT, ctr);

  fc_softmax<<<dim3(BB), dim3(64), 0, stream>>>(hT, W_fc, b_fc, out);
}

// Round 10
// 1451.530 us; speedup vs baseline: 1.9747x; 1.9747x over previous
//
#include <hip/hip_runtime.h>

// Problem constants
#define TT 512
#define BB 256
#define II 128
#define HH 256
#define CC 10

typedef __attribute__((ext_vector_type(8))) _Float16 f16x8;
typedef __attribute__((ext_vector_type(4))) _Float16 f16x4;
typedef __attribute__((ext_vector_type(4))) float    f32x4;

__device__ __forceinline__ float fsig(float x){ return 1.0f/(1.0f+__expf(-x)); }
__device__ __forceinline__ float ftanh(float x){ return 2.0f/(1.0f+__expf(-2.0f*x)) - 1.0f; }

// ---- Scope-templated sync/publish primitives (R7-proven, 1476us) ----------
// FAST=false: agent scope (IF$ coherence point) — always correct.
// FAST=true : XCD scope (local L2) — only when the runtime handshake proves
//             all 32 communicating waves of a group-pair share one XCD.
// Session HW facts: RMW observes RMW/stores promptly; spinning LOADS never
// do (R9/R10). In-wave interleaving of chains always loses (R6/R12).
// R13 deltas vs R7: poll sleep 2->1 (finer detection on the pacing chain);
// L1 waves run at s_setprio(1) (they pace the pipeline: more MFMAs + the
// kernel ends when L1 ends; bias SIMD issue on the shared CU toward them).

template<bool FAST>
__device__ __forceinline__ unsigned cpoll(unsigned* p){
  unsigned v;
  if constexpr(FAST){
    unsigned z = 0u;
    // returning atomic (sc0 = return old), NO sc1 -> executes at local L2
    asm volatile("global_atomic_add %0, %1, %2, off sc0\n\ts_waitcnt vmcnt(0)"
                 : "=v"(v) : "v"(p), "v"(z) : "memory");
  } else {
    v = __hip_atomic_fetch_add(p, 0u, __ATOMIC_RELAXED, __HIP_MEMORY_SCOPE_AGENT);
  }
  return v;
}
// Wave-level poll: lane0 spins, result broadcast. No __syncthreads needed.
template<bool FAST>
__device__ __forceinline__ unsigned poll_until(unsigned* p, unsigned tgt){
  unsigned v = 0;
  if((threadIdx.x & 63) == 0){
    v = cpoll<FAST>(p);
    while(v < tgt){
      __builtin_amdgcn_s_sleep(FAST ? 1 : 2);   // R13: finer detect on fast path
      v = cpoll<FAST>(p);
    }
  }
  unsigned u = __builtin_amdgcn_readfirstlane(v);
  asm volatile("" ::: "memory");   // fence subsequent loads below the poll
  return u;
}
// Fire-and-forget arrive (+1). FAST: returnless atomic at local L2.
template<bool FAST>
__device__ __forceinline__ void arrive1(unsigned* p){
  if constexpr(FAST){
    unsigned one = 1u;
    asm volatile("global_atomic_add %0, %1, off" :: "v"(p), "v"(one) : "memory");
  } else {
    (void)__hip_atomic_fetch_add(p, 1u, __ATOMIC_RELAXED, __HIP_MEMORY_SCOPE_AGENT);
  }
}
// Publish h. FAST: plain store -> lands in local L2 (consumers bypass L1).
// slow: write-through to IF$ (sc0 sc1) — proven visibility.
template<bool FAST>
__device__ __forceinline__ void store_h16(_Float16* p, _Float16 vv){
  unsigned b32 = (unsigned)__builtin_bit_cast(unsigned short, vv);
  if constexpr(FAST)
    asm volatile("global_store_short %0, %1, off" :: "v"(p), "v"(b32) : "memory");
  else
    asm volatile("global_store_short %0, %1, off sc0 sc1" :: "v"(p), "v"(b32) : "memory");
}
// Ring loads (addresses reused every 4 steps -> must bypass CU L1).
// FAST: sc0 only (read local L2). slow: sc0 sc1 (read IF$).
template<bool FAST>
__device__ __forceinline__ f16x8 load_ring(const _Float16* p){
  f16x8 r;
  if constexpr(FAST)
    asm volatile("global_load_dwordx4 %0, %1, off sc0" : "=v"(r) : "v"(p) : "memory");
  else
    asm volatile("global_load_dwordx4 %0, %1, off sc0 sc1" : "=v"(r) : "v"(p) : "memory");
  return r;
}
// Pin a loaded fragment: value becomes asm-defined -> compiler cannot
// rematerialize the load inside the loop (the R2/R3 failure mode).
#define PIN(x) asm volatile("" : "+v"(x))

// One WAVE owns: 16 samples (group gb) x 16 units (gj) x ALL 4 gates.
// 4 independent MFMA chains; all 4 gate values for a cell end up in one lane
// (D: row(sample)=quad*4+r, col(unit)=l15) -> elementwise is wave-local.
// Weights fp16, VGPR-resident (pinned). Cross-wave h exchange via L2/IF$ with
// per-group monotonic counters; wave-level arrive/poll, zero barriers.
template<int KXT, bool IS_L1, bool FAST>
__device__ __forceinline__ void run_wave(
    const _Float16* __restrict__ xin,   // L0: xc [B][T][I] ; L1: h0 [T][B][H]
    const _Float16* __restrict__ Wh,    // fp16 [4H][H]
    const _Float16* __restrict__ Wx,    // fp16 [4H][KXT*32]
    const float* __restrict__ b_ih, const float* __restrict__ b_hh,
    const int* __restrict__ lengths,
    _Float16* __restrict__ hbuf,        // L0: h0 full [T][B][H]; L1: ring [4][B][H]
    float* __restrict__ hT,
    unsigned* cown, unsigned* cprod, int gb, int gj)
{
  constexpr int KXV = KXT*32;
  const int lane = threadIdx.x & 63;
  const int quad = lane >> 4;
  const int l15  = lane & 15;
  const int koff = quad << 3;          // k = quad*8 + j in a 32-wide k-tile
  const int b0   = gb << 4;
  const int u    = (gj << 4) + l15;    // this lane's unit (B col / D col)

  // Stationary weight fragments: B[k][n] = W[g*H+u][k]; pinned in VGPRs.
  f16x8 wh[4][8], wx[4][KXT];
  float bias[4];
#pragma unroll
  for(int g=0; g<4; ++g){
    const int row = g*HH + u;
#pragma unroll
    for(int kt=0; kt<8; ++kt){
      wh[g][kt] = *(const f16x8*)(Wh + (size_t)row*HH + kt*32 + koff);
      PIN(wh[g][kt]);
    }
#pragma unroll
    for(int kt=0; kt<KXT; ++kt){
      wx[g][kt] = *(const f16x8*)(Wx + (size_t)row*KXV + kt*32 + koff);
      PIN(wx[g][kt]);
    }
    bias[g] = b_ih[row] + b_hh[row];
  }

  // Each lane owns 4 cells: samples b0+quad*4+r, unit u. fp32 state in regs.
  int sb[4], len[4]; float cs[4], hs[4];
#pragma unroll
  for(int r=0; r<4; ++r){
    sb[r]  = b0 + (quad<<2) + r;
    len[r] = lengths[sb[r]];
    cs[r] = 0.f; hs[r] = 0.f;
  }

  unsigned lastp = 0, lasto = 0;   // monotone counter caches (skip poll when ok)

  f16x8 axn[KXT];
  if(!IS_L1){
    const _Float16* xp = xin + ((size_t)(b0+l15)*TT + 0)*KXV + koff;
#pragma unroll
    for(int kt=0; kt<KXT; ++kt) axn[kt] = *(const f16x8*)(xp + kt*32);
  }

  for(int t=0; t<TT; ++t){
    // ---- x-part input fragments
    f16x8 ax[KXT];
    if(IS_L1){
      const unsigned tgtp = 16u*(unsigned)(t+1);          // L0 group done step t
      if(lastp < tgtp) lastp = poll_until<FAST>(cprod, tgtp);
      const _Float16* xp = xin + ((size_t)t*BB + b0 + l15)*HH + koff;
      // fresh addresses each t -> plain cached load is safe in both modes
      // (L1 miss -> L2 hit on the producer's dirty line / IF$ fill)
#pragma unroll
      for(int kt=0; kt<KXT; ++kt) ax[kt] = *(const f16x8*)(xp + kt*32);
    } else {
#pragma unroll
      for(int kt=0; kt<KXT; ++kt) ax[kt] = axn[kt];
    }

    // ---- wait own group peers (h[t-1] complete), then issue h loads
    if(t > 0){
      const unsigned tgto = 16u*(unsigned)t;
      if(lasto < tgto) lasto = poll_until<FAST>(cown, tgto);
    }
    f16x8 ah[8];
    if(t > 0){
      if(IS_L1){
        const _Float16* hp = hbuf + (((size_t)((t-1)&3))*BB + b0 + l15)*HH + koff;
#pragma unroll
        for(int kt=0; kt<8; ++kt) ah[kt] = load_ring<FAST>(hp + kt*32);
      } else {
        const _Float16* hp = hbuf + ((size_t)(t-1)*BB + b0 + l15)*HH + koff;
#pragma unroll
        for(int kt=0; kt<8; ++kt) ah[kt] = *(const f16x8*)(hp + kt*32);
      }
    }

    // ---- x-MFMAs run under the h-load latency
    f32x4 acc[4];
#pragma unroll
    for(int g=0; g<4; ++g) acc[g] = (f32x4){bias[g],bias[g],bias[g],bias[g]};
#pragma unroll
    for(int kt=0; kt<KXT; ++kt)
#pragma unroll
      for(int g=0; g<4; ++g)
        acc[g] = __builtin_amdgcn_mfma_f32_16x16x32_f16(ax[kt], wx[g][kt], acc[g], 0,0,0);

    if(t > 0){
      if(IS_L1){
        // asm loads: compiler doesn't know a wait is needed -> tie regs to it
        asm volatile("s_waitcnt vmcnt(0)"
          : "+v"(ah[0]),"+v"(ah[1]),"+v"(ah[2]),"+v"(ah[3]),
            "+v"(ah[4]),"+v"(ah[5]),"+v"(ah[6]),"+v"(ah[7]) :: "memory");
      }
#pragma unroll
      for(int kt=0; kt<8; ++kt)
#pragma unroll
        for(int g=0; g<4; ++g)
          acc[g] = __builtin_amdgcn_mfma_f32_16x16x32_f16(ah[kt], wh[g][kt], acc[g], 0,0,0);
    }

    // ---- elementwise cell update (all gates in-lane, no exchange)
#pragma unroll
    for(int r=0; r<4; ++r){
      float iv = fsig (acc[0][r]);
      float fv = fsig (acc[1][r]);
      float gv = ftanh(acc[2][r]);
      float ov = fsig (acc[3][r]);
      float cn = fv*cs[r] + iv*gv;
      float hn = ov*ftanh(cn);
      if(t < len[r]){ cs[r] = cn; hs[r] = hn; }   // freeze past length
      _Float16* hp = IS_L1
        ? hbuf + (((size_t)(t&3))*BB + sb[r])*HH + u
        : hbuf + ((size_t)t*BB + sb[r])*HH + u;
      store_h16<FAST>(hp, (_Float16)hs[r]);
      if(IS_L1 && t == TT-1) hT[(size_t)sb[r]*HH + u] = hs[r];
    }

    // ---- drain own stores (L2/IF$ accepted), arrive (off critical path)
    asm volatile("s_waitcnt vmcnt(0)" ::: "memory");
    if(lane == 0) arrive1<FAST>(cown);

    // ---- prefetch next x AFTER the drain so it isn't waited on; lands
    //      during the next poll window
    if(!IS_L1 && t+1 < TT){
      const _Float16* xp = xin + ((size_t)(b0+l15)*TT + (t+1))*KXV + koff;
#pragma unroll
      for(int kt=0; kt<KXT; ++kt) axn[kt] = *(const f16x8*)(xp + kt*32);
    }
  }
}

// 512 single-wave WGs: layer = blk>>8, gb = blk&15, gj = (blk>>4)&15.
// blk%8 == gb%8 -> a group's 16 waves AND its partner-layer group share an
// XCD under round-robin dispatch. Startup handshake VERIFIES this (via
// HW_REG_XCC_ID) and selects the L2-scope fast path only when true;
// otherwise the proven agent-scope path runs — correctness never depends
// on dispatch placement (G16), only speed does.
__global__ __launch_bounds__(64, 1)
void lstm_fused(const _Float16* __restrict__ xc,
                const _Float16* __restrict__ Wh0, const _Float16* __restrict__ Wx0,
                const _Float16* __restrict__ Wh1, const _Float16* __restrict__ Wx1,
                const float* __restrict__ b_ih0, const float* __restrict__ b_hh0,
                const float* __restrict__ b_ih1, const float* __restrict__ b_hh1,
                const int* __restrict__ lens,
                _Float16* __restrict__ h0seq, _Float16* __restrict__ h1ring,
                float* __restrict__ hT, unsigned* __restrict__ ctr)
{
  const int blk   = blockIdx.x;
  const int layer = blk >> 8;
  const int gb    = blk & 15;
  const int gj    = (blk >> 4) & 15;
  const int lane  = threadIdx.x & 63;
  unsigned* c0    = ctr + gb*32;          // 128B-padded counters
  unsigned* c1    = ctr + (16+gb)*32;
  unsigned* xcds  = ctr + 1024;           // [512] published XCC ids (ws+4K)
  unsigned* cinit = ctr + 1536;           // startup barrier counter (ws+6K)

  // ---- one-time colocation handshake (agent scope, proven primitives) ----
  unsigned myx;
  asm volatile("s_getreg_b32 %0, hwreg(HW_REG_XCC_ID)" : "=s"(myx));
  if(lane == 0){
    asm volatile("global_store_dword %0, %1, off sc0 sc1" :: "v"(xcds + blk), "v"(myx) : "memory");
    asm volatile("s_waitcnt vmcnt(0)" ::: "memory");
    (void)__hip_atomic_fetch_add(cinit, 1u, __ATOMIC_RELAXED, __HIP_MEMORY_SCOPE_AGENT);
  }
  unsigned iv = 0;
  if(lane == 0){
    iv = __hip_atomic_fetch_add(cinit, 0u, __ATOMIC_RELAXED, __HIP_MEMORY_SCOPE_AGENT);
    while(iv < 512u){ __builtin_amdgcn_s_sleep(8);
      iv = __hip_atomic_fetch_add(cinit, 0u, __ATOMIC_RELAXED, __HIP_MEMORY_SCOPE_AGENT); }
  }
  (void)__builtin_amdgcn_readfirstlane(iv);
  asm volatile("" ::: "memory");
  // lanes 0..31 each check one of the 32 waves of this group-pair
  unsigned pv = myx;
  if(lane < 32){
    const unsigned* pp = xcds + ((lane < 16) ? (gb + 16*lane)
                                             : (256 + gb + 16*(lane-16)));
    asm volatile("global_load_dword %0, %1, off sc0 sc1\n\ts_waitcnt vmcnt(0)"
                 : "=v"(pv) : "v"(pp) : "memory");
  }
  const bool fast = (__ballot(pv == myx) == ~0ull);

  // R13: L1 waves pace the pipeline (more MFMAs; kernel ends when L1 ends).
  // Bias SIMD issue toward them on the shared CU.
  if(layer == 1) __builtin_amdgcn_s_setprio(1);

  if(layer == 0){
    if(fast) run_wave<4,false,true >(xc, Wh0, Wx0, b_ih0, b_hh0, lens, h0seq,
                                     nullptr, c0, nullptr, gb, gj);
    else     run_wave<4,false,false>(xc, Wh0, Wx0, b_ih0, b_hh0, lens, h0seq,
                                     nullptr, c0, nullptr, gb, gj);
  } else {
    if(fast) run_wave<8,true ,true >(h0seq, Wh1, Wx1, b_ih1, b_hh1, lens, h1ring,
                                     hT, c1, c0, gb, gj);
    else     run_wave<8,true ,false>(h0seq, Wh1, Wx1, b_ih1, b_hh1, lens, h1ring,
                                     hT, c1, c0, gb, gj);
  }
}

// fp32 -> fp16 elementwise convert (vectorized x4)
__global__ __launch_bounds__(256)
void cvt4(const float* __restrict__ in, _Float16* __restrict__ out, int n4)
{
  int i = blockIdx.x*256 + threadIdx.x;
  if(i < n4){
    float4 v = ((const float4*)in)[i];
    f16x4 o;
    o[0]=(_Float16)v.x; o[1]=(_Float16)v.y; o[2]=(_Float16)v.z; o[3]=(_Float16)v.w;
    ((f16x4*)out)[i] = o;
  }
}

// logits = hT @ W_fc^T + b_fc ; softmax over 10 classes. One wave per sample.
__global__ __launch_bounds__(64)
void fc_softmax(const float* __restrict__ hT,
                const float* __restrict__ W_fc,
                const float* __restrict__ b_fc,
                float* __restrict__ out)
{
  const int b = blockIdx.x;
  const int lane = threadIdx.x;
  float p[CC];
#pragma unroll
  for (int c = 0; c < CC; ++c) p[c] = 0.f;
  const float* hb = hT + b * HH;
  for (int k = lane; k < HH; k += 64){
    float hv = hb[k];
#pragma unroll
    for (int c = 0; c < CC; ++c) p[c] += hv * W_fc[c * HH + k];
  }
#pragma unroll
  for (int c = 0; c < CC; ++c){
#pragma unroll
    for (int off = 32; off > 0; off >>= 1) p[c] += __shfl_down(p[c], off);
  }
  if (lane == 0){
    float m = -1e30f;
#pragma unroll
    for (int c = 0; c < CC; ++c){ p[c] += b_fc[c]; m = fmaxf(m, p[c]); }
    float ssum = 0.f;
#pragma unroll
    for (int c = 0; c < CC; ++c){ p[c] = __expf(p[c] - m); ssum += p[c]; }
    float inv = 1.0f / ssum;
#pragma unroll
    for (int c = 0; c < CC; ++c) out[b * CC + c] = p[c] * inv;
  }
}

extern "C" void kernel_launch(void* const* d_in, const int* in_sizes, int n_in,
                              void* d_out, int out_size, void* d_ws, size_t ws_size,
                              hipStream_t stream) {
  const float* x      = (const float*)d_in[0];   // [B][T][I]
  const int*   lens   = (const int*)  d_in[1];   // [B]
  const float* W_fc   = (const float*)d_in[2];   // [C][H]
  const float* b_fc   = (const float*)d_in[3];   // [C]
  const float* W_ih0  = (const float*)d_in[4];   // [4H][I]
  const float* W_hh0  = (const float*)d_in[5];   // [4H][H]
  const float* b_ih0  = (const float*)d_in[6];
  const float* b_hh0  = (const float*)d_in[7];
  const float* W_ih1  = (const float*)d_in[8];   // [4H][H]
  const float* W_hh1  = (const float*)d_in[9];
  const float* b_ih1  = (const float*)d_in[10];
  const float* b_hh1  = (const float*)d_in[11];
  float* out = (float*)d_out;

  char* ws = (char*)d_ws;
  // ws layout (bytes):
  //   [0, 4K)          counters (2 layers x 16 groups x 128B)
  //   [4K, 6K)         xcds[512] (handshake)
  //   [6K, 8K)         cinit barrier counter
  //   [8K, +256K)      hT fp32
  //   [270336 ..)      fp16 weights: Wh0(512K) Wx0(256K) Wh1(512K) Wx1(512K)
  //   [2105344 ..)     xc fp16 [B][T][I]  (32 MB)
  //   [35659776 ..)    h0seq fp16 [T][B][H] (64 MB)
  //   [102768640 ..)   h1 ring fp16 [4][B][H] (512 KB)   total ~103 MB
  unsigned* ctr  = (unsigned*)ws;
  float*    hT   = (float*)(ws + 8192);
  _Float16* Wh0c = (_Float16*)(ws + 270336);
  _Float16* Wx0c = (_Float16*)(ws + 794624);
  _Float16* Wh1c = (_Float16*)(ws + 1056768);
  _Float16* Wx1c = (_Float16*)(ws + 1581056);
  _Float16* xc   = (_Float16*)(ws + 2105344);
  _Float16* h0   = (_Float16*)(ws + 35659776);
  _Float16* h1r  = (_Float16*)(ws + 102768640);

  hipMemsetAsync(ws, 0, 8192, stream);   // zero counters + handshake each launch

  // prep: fp32 -> fp16 (weights + x), removes all in-loop conversion work
  cvt4<<<dim3((BB*TT*II/4 + 255)/256), dim3(256), 0, stream>>>(x,     xc,   BB*TT*II/4);
  cvt4<<<dim3((4*HH*HH/4  + 255)/256), dim3(256), 0, stream>>>(W_hh0, Wh0c, 4*HH*HH/4);
  cvt4<<<dim3((4*HH*II/4  + 255)/256), dim3(256), 0, stream>>>(W_ih0, Wx0c, 4*HH*II/4);
  cvt4<<<dim3((4*HH*HH/4  + 255)/256), dim3(256), 0, stream>>>(W_hh1, Wh1c, 4*HH*HH/4);
  cvt4<<<dim3((4*HH*HH/4  + 255)/256), dim3(256), 0, stream>>>(W_ih1, Wx1c, 4*HH*HH/4);

  lstm_fused<<<dim3(512), dim3(64), 0, stream>>>(
      xc, Wh0c, Wx0c, Wh1c, Wx1c, b_ih0, b_hh0, b_ih1, b_hh1, lens,
      h0, h1r, hT, ctr);

  fc_softmax<<<dim3(BB), dim3(64), 0, stream>>>(hT, W_fc, b_fc, out);
}